// Round 1
// baseline (489.050 us; speedup 1.0000x reference)
//
#include <hip/hip_runtime.h>
#include <math.h>
#include <stdint.h>

#define B_ 2
#define S_ 1024
#define D_ 1024
#define H_ 2048
#define E_ 8
#define TOK_ (B_*S_)      // 2048 tokens
#define N1_ (2*H_)        // 4096
#define PAIRS_ (TOK_*2)   // 4096 (token, expert-slot) pairs

typedef float f32x4 __attribute__((ext_vector_type(4)));
typedef short short8 __attribute__((ext_vector_type(8)));

__device__ __forceinline__ unsigned short f2bf(float f) {
  unsigned int u = __float_as_uint(f);
  u += 0x7fffu + ((u >> 16) & 1u);   // RNE
  return (unsigned short)(u >> 16);
}

// ---------------------------------------------------------------------------
// Transpose + fp32->bf16 convert: src fp32 [E][R][C] -> dst bf16 [E][C][R]
// ---------------------------------------------------------------------------
__global__ __launch_bounds__(256) void transpose_f32_to_bf16(
    const float* __restrict__ src, unsigned short* __restrict__ dst, int R, int C)
{
  __shared__ float tile[64][65];
  const int e = blockIdx.z;
  const float* s = src + (size_t)e * R * C;
  unsigned short* d = dst + (size_t)e * R * C;
  const int c0 = blockIdx.x * 64, r0 = blockIdx.y * 64;
  const int tx = threadIdx.x & 63;
  const int ty = threadIdx.x >> 6;
#pragma unroll
  for (int i = 0; i < 16; ++i) {
    int r = ty + i * 4;
    tile[r][tx] = s[(size_t)(r0 + r) * C + c0 + tx];
  }
  __syncthreads();
#pragma unroll
  for (int i = 0; i < 16; ++i) {
    int c = ty + i * 4;
    d[(size_t)(c0 + c) * R + r0 + tx] = f2bf(tile[tx][c]);
  }
}

// ---------------------------------------------------------------------------
// Router: logits (fp32 exact), sigmoid, top-2, slot assignment, aux partials
// ---------------------------------------------------------------------------
__global__ __launch_bounds__(256) void router_kernel(
    const float* __restrict__ x, const float* __restrict__ rw,
    const float* __restrict__ rb, int* __restrict__ counts,
    int* __restrict__ expert_of, int* __restrict__ slot_of,
    float* __restrict__ w_of, float* __restrict__ tok_ssq)
{
  const int wave = threadIdx.x >> 6, lane = threadIdx.x & 63;
  const int t = blockIdx.x * 4 + wave;   // one wave per token
  const float* xr = x + (size_t)t * D_;
  float acc[E_];
#pragma unroll
  for (int e = 0; e < E_; ++e) acc[e] = 0.f;
  for (int d = lane; d < D_; d += 64) {
    float xv = xr[d];
#pragma unroll
    for (int e = 0; e < E_; ++e) acc[e] += xv * rw[e * D_ + d];
  }
#pragma unroll
  for (int e = 0; e < E_; ++e) {
    float v = acc[e];
#pragma unroll
    for (int sh = 32; sh > 0; sh >>= 1) v += __shfl_xor(v, sh, 64);
    acc[e] = v;
  }
  if (lane == 0) {
    float logits[E_], sc[E_], ssq = 0.f;
#pragma unroll
    for (int e = 0; e < E_; ++e) {
      logits[e] = acc[e] + rb[e];
      ssq += logits[e] * logits[e];
      sc[e] = 1.f / (1.f + __expf(-logits[e]));
    }
    tok_ssq[t] = ssq;
    int i1 = 0;
#pragma unroll
    for (int e = 1; e < E_; ++e) if (sc[e] > sc[i1]) i1 = e;     // ties -> low idx
    int i2 = (i1 == 0) ? 1 : 0;
#pragma unroll
    for (int e = 0; e < E_; ++e)
      if (e != i1 && e != i2 && sc[e] > sc[i2]) i2 = e;
    float v1 = sc[i1], v2 = sc[i2];
    float inv = 1.f / (v1 + v2 + 1e-6f);
    int s1 = atomicAdd(&counts[i1], 1);
    int s2 = atomicAdd(&counts[i2], 1);
    expert_of[t * 2]     = i1; slot_of[t * 2]     = s1; w_of[t * 2]     = v1 * inv;
    expert_of[t * 2 + 1] = i2; slot_of[t * 2 + 1] = s2; w_of[t * 2 + 1] = v2 * inv;
  }
}

__global__ void offsets_kernel(const int* __restrict__ counts, int* __restrict__ offsets)
{
  if (threadIdx.x == 0) {
    int o = 0;
    for (int e = 0; e < E_; ++e) { offsets[e] = o; o += counts[e]; }
  }
}

__global__ __launch_bounds__(256) void aux_kernel(const float* __restrict__ tok_ssq,
                                                  float* __restrict__ out_aux)
{
  __shared__ float sm[256];
  float s = 0.f;
  for (int i = threadIdx.x; i < TOK_; i += 256) s += tok_ssq[i];
  sm[threadIdx.x] = s;
  __syncthreads();
  for (int h = 128; h > 0; h >>= 1) {
    if (threadIdx.x < h) sm[threadIdx.x] += sm[threadIdx.x + h];
    __syncthreads();
  }
  if (threadIdx.x == 0) *out_aux = 0.01f * sm[0] / (float)(TOK_ * E_);
}

// ---------------------------------------------------------------------------
// Pack: gather selected token rows (fp32 -> bf16) into compacted A matrix
// ---------------------------------------------------------------------------
__global__ __launch_bounds__(256) void pack_kernel(
    const float* __restrict__ x, const int* __restrict__ expert_of,
    const int* __restrict__ slot_of, const float* __restrict__ w_of,
    const int* __restrict__ offsets, unsigned short* __restrict__ px,
    int* __restrict__ tok_ids, float* __restrict__ tok_w)
{
  const int pair = blockIdx.x;
  const int t = pair >> 1;
  const int e = expert_of[pair];
  const int row = offsets[e] + slot_of[pair];
  if (threadIdx.x == 0) { tok_ids[row] = t; tok_w[row] = w_of[pair]; }
  const float4* xr = (const float4*)(x + (size_t)t * D_);
  ushort4* pr = (ushort4*)(px + (size_t)row * D_);
  float4 v = xr[threadIdx.x];              // 256 threads x 4 = 1024 elems
  ushort4 o;
  o.x = f2bf(v.x); o.y = f2bf(v.y); o.z = f2bf(v.z); o.w = f2bf(v.w);
  pr[threadIdx.x] = o;
}

// ---------------------------------------------------------------------------
// GEMM staging: 128-row x 32-col bf16 tile, global_load_lds width-16
// LDS layout [row][32] contiguous (matches lane order: lane>>2=row, lane&3=16B seg)
// ---------------------------------------------------------------------------
__device__ __forceinline__ void stage_tile(const unsigned short* gbase, int gstride,
                                           unsigned short* sbase, int kk,
                                           int wave, int lane)
{
#pragma unroll
  for (int c = 0; c < 2; ++c) {
    const unsigned short* g = gbase
        + (size_t)(wave * 32 + c * 16 + (lane >> 2)) * gstride + kk + (lane & 3) * 8;
    unsigned short* s = sbase + (wave * 32 + c * 16) * 32;   // wave-uniform base
    __builtin_amdgcn_global_load_lds(
        (const __attribute__((address_space(1))) void*)g,
        (__attribute__((address_space(3))) void*)s, 16, 0, 0);
  }
}

// ---------------------------------------------------------------------------
// GEMM1 + fused SwiGLU: hid[row][h] = silu(px@w1)[row][h] * (px@w2)[row][h]
// Block: 128 rows x 128 hidden cols (paired tiles h and h+2048). 4 waves 2x2.
// ---------------------------------------------------------------------------
__global__ __launch_bounds__(256, 2) void gemm1_kernel(
    const unsigned short* __restrict__ px, const unsigned short* __restrict__ w12t,
    unsigned short* __restrict__ hid, const int* __restrict__ counts,
    const int* __restrict__ offsets)
{
  const int e = blockIdx.z, mt = blockIdx.y, nt = blockIdx.x;
  const int cnt = counts[e];
  if (mt * 128 >= cnt) return;
  const int off = offsets[e];
  const int tid = threadIdx.x;
  const int wave = tid >> 6, lane = tid & 63;
  const int wm = wave >> 1, wn = wave & 1;
  const int lr = lane & 15, lk = lane >> 4;

  __shared__ __align__(16) unsigned short As[128 * 32];
  __shared__ __align__(16) unsigned short B1s[128 * 32];
  __shared__ __align__(16) unsigned short B2s[128 * 32];

  f32x4 zero = {0.f, 0.f, 0.f, 0.f};
  f32x4 acc1[4][4], acc2[4][4];
#pragma unroll
  for (int mi = 0; mi < 4; ++mi)
#pragma unroll
    for (int ni = 0; ni < 4; ++ni) { acc1[mi][ni] = zero; acc2[mi][ni] = zero; }

  const unsigned short* Abase  = px + (size_t)(off + mt * 128) * D_;
  const unsigned short* B1base = w12t + ((size_t)e * N1_ + nt * 128) * D_;
  const unsigned short* B2base = w12t + ((size_t)e * N1_ + H_ + nt * 128) * D_;

  for (int kk = 0; kk < D_; kk += 32) {
    stage_tile(Abase, D_, As, kk, wave, lane);
    stage_tile(B1base, D_, B1s, kk, wave, lane);
    stage_tile(B2base, D_, B2s, kk, wave, lane);
    __syncthreads();
    short8 a[4], b1[4], b2[4];
#pragma unroll
    for (int i = 0; i < 4; ++i) {
      a[i]  = *(const short8*)&As[(wm * 64 + i * 16 + lr) * 32 + lk * 8];
      b1[i] = *(const short8*)&B1s[(wn * 64 + i * 16 + lr) * 32 + lk * 8];
      b2[i] = *(const short8*)&B2s[(wn * 64 + i * 16 + lr) * 32 + lk * 8];
    }
#pragma unroll
    for (int mi = 0; mi < 4; ++mi)
#pragma unroll
      for (int ni = 0; ni < 4; ++ni) {
        acc1[mi][ni] = __builtin_amdgcn_mfma_f32_16x16x32_bf16(a[mi], b1[ni], acc1[mi][ni], 0, 0, 0);
        acc2[mi][ni] = __builtin_amdgcn_mfma_f32_16x16x32_bf16(a[mi], b2[ni], acc2[mi][ni], 0, 0, 0);
      }
    __syncthreads();
  }

  // epilogue: SwiGLU + bf16 store (C/D layout: col=lane&15, row=(lane>>4)*4+r)
#pragma unroll
  for (int mi = 0; mi < 4; ++mi)
#pragma unroll
    for (int r = 0; r < 4; ++r) {
      int row_local = mt * 128 + wm * 64 + mi * 16 + lk * 4 + r;
      if (row_local < cnt) {
#pragma unroll
        for (int ni = 0; ni < 4; ++ni) {
          int col = nt * 128 + wn * 64 + ni * 16 + lr;
          float v1 = acc1[mi][ni][r];
          float v2 = acc2[mi][ni][r];
          float hval = (v1 / (1.f + __expf(-v1))) * v2;
          hid[(size_t)(off + row_local) * H_ + col] = f2bf(hval);
        }
      }
    }
}

// ---------------------------------------------------------------------------
// GEMM2: out[tok] += weight * (hid @ w3t^T)
// ---------------------------------------------------------------------------
__global__ __launch_bounds__(256, 2) void gemm2_kernel(
    const unsigned short* __restrict__ hid, const unsigned short* __restrict__ w3t,
    const int* __restrict__ counts, const int* __restrict__ offsets,
    const int* __restrict__ tok_ids, const float* __restrict__ tok_w,
    float* __restrict__ out)
{
  const int e = blockIdx.z, mt = blockIdx.y, nt = blockIdx.x;
  const int cnt = counts[e];
  if (mt * 128 >= cnt) return;
  const int off = offsets[e];
  const int tid = threadIdx.x;
  const int wave = tid >> 6, lane = tid & 63;
  const int wm = wave >> 1, wn = wave & 1;
  const int lr = lane & 15, lk = lane >> 4;

  __shared__ __align__(16) unsigned short As[128 * 32];
  __shared__ __align__(16) unsigned short Bs[128 * 32];

  f32x4 zero = {0.f, 0.f, 0.f, 0.f};
  f32x4 acc[4][4];
#pragma unroll
  for (int mi = 0; mi < 4; ++mi)
#pragma unroll
    for (int ni = 0; ni < 4; ++ni) acc[mi][ni] = zero;

  const unsigned short* Abase = hid + (size_t)(off + mt * 128) * H_;
  const unsigned short* Bbase = w3t + ((size_t)e * D_ + nt * 128) * H_;

  for (int kk = 0; kk < H_; kk += 32) {
    stage_tile(Abase, H_, As, kk, wave, lane);
    stage_tile(Bbase, H_, Bs, kk, wave, lane);
    __syncthreads();
    short8 a[4], b[4];
#pragma unroll
    for (int i = 0; i < 4; ++i) {
      a[i] = *(const short8*)&As[(wm * 64 + i * 16 + lr) * 32 + lk * 8];
      b[i] = *(const short8*)&Bs[(wn * 64 + i * 16 + lr) * 32 + lk * 8];
    }
#pragma unroll
    for (int mi = 0; mi < 4; ++mi)
#pragma unroll
      for (int ni = 0; ni < 4; ++ni)
        acc[mi][ni] = __builtin_amdgcn_mfma_f32_16x16x32_bf16(a[mi], b[ni], acc[mi][ni], 0, 0, 0);
    __syncthreads();
  }

#pragma unroll
  for (int mi = 0; mi < 4; ++mi)
#pragma unroll
    for (int r = 0; r < 4; ++r) {
      int row_local = mt * 128 + wm * 64 + mi * 16 + lk * 4 + r;
      if (row_local < cnt) {
        int g = off + row_local;
        int t = tok_ids[g];
        float wgt = tok_w[g];
#pragma unroll
        for (int ni = 0; ni < 4; ++ni) {
          int col = nt * 128 + wn * 64 + ni * 16 + lr;
          atomicAdd(&out[(size_t)t * D_ + col], acc[mi][ni][r] * wgt);
        }
      }
    }
}

// ---------------------------------------------------------------------------
extern "C" void kernel_launch(void* const* d_in, const int* in_sizes, int n_in,
                              void* d_out, int out_size, void* d_ws, size_t ws_size,
                              hipStream_t stream)
{
  const float* x   = (const float*)d_in[0];
  const float* rw  = (const float*)d_in[1];
  const float* rb  = (const float*)d_in[2];
  const float* w12 = (const float*)d_in[3];
  const float* w3  = (const float*)d_in[4];
  float* out = (float*)d_out;

  // workspace layout (~120.1 MB total)
  char* wsb = (char*)d_ws;
  int*   counts    = (int*)(wsb + 0);                 // 8 ints
  int*   offsets   = (int*)(wsb + 64);                // 8 ints
  int*   expert_of = (int*)(wsb + 1024);              // 4096 ints
  int*   slot_of   = (int*)(wsb + 1024 + 16384);
  float* w_of      = (float*)(wsb + 1024 + 2 * 16384);
  int*   tok_ids   = (int*)(wsb + 1024 + 3 * 16384);
  float* tok_w     = (float*)(wsb + 1024 + 4 * 16384);
  float* tok_ssq   = (float*)(wsb + 1024 + 5 * 16384);        // 2048 floats
  unsigned short* px   = (unsigned short*)(wsb + (128 << 10));                          // 8 MB
  unsigned short* hid  = (unsigned short*)(wsb + (128 << 10) + ((size_t)8  << 20));     // 16 MB
  unsigned short* w12t = (unsigned short*)(wsb + (128 << 10) + ((size_t)24 << 20));     // 64 MB
  unsigned short* w3t  = (unsigned short*)(wsb + (128 << 10) + ((size_t)88 << 20));     // 32 MB

  hipMemsetAsync(counts, 0, E_ * sizeof(int), stream);
  hipMemsetAsync(out, 0, (size_t)out_size * sizeof(float), stream);

  transpose_f32_to_bf16<<<dim3(N1_ / 64, D_ / 64, E_), 256, 0, stream>>>(w12, w12t, D_, N1_);
  transpose_f32_to_bf16<<<dim3(D_ / 64, H_ / 64, E_), 256, 0, stream>>>(w3, w3t, H_, D_);
  router_kernel<<<TOK_ / 4, 256, 0, stream>>>(x, rw, rb, counts, expert_of, slot_of, w_of, tok_ssq);
  offsets_kernel<<<1, 64, 0, stream>>>(counts, offsets);
  aux_kernel<<<1, 256, 0, stream>>>(tok_ssq, out + (size_t)TOK_ * D_);
  pack_kernel<<<PAIRS_, 256, 0, stream>>>(x, expert_of, slot_of, w_of, offsets, px, tok_ids, tok_w);
  gemm1_kernel<<<dim3(16, 16, 8), 256, 0, stream>>>(px, w12t, hid, counts, offsets);
  gemm2_kernel<<<dim3(8, 16, 8), 256, 0, stream>>>(hid, w3t, counts, offsets, tok_ids, tok_w, out);
}

// Round 2
// 445.710 us; speedup vs baseline: 1.0972x; 1.0972x over previous
//
#include <hip/hip_runtime.h>
#include <math.h>
#include <stdint.h>

#define B_ 2
#define S_ 1024
#define D_ 1024
#define H_ 2048
#define E_ 8
#define TOK_ (B_*S_)      // 2048 tokens
#define N1_ (2*H_)        // 4096
#define PAIRS_ (TOK_*2)   // 4096 (token, expert-slot) pairs
#define MAXTILES_ 40      // max sum of ceil(cnt_e/128) = 32 + 7

typedef float f32x4 __attribute__((ext_vector_type(4)));
typedef short short8 __attribute__((ext_vector_type(8)));

__device__ __forceinline__ unsigned short f2bf(float f) {
  unsigned int u = __float_as_uint(f);
  u += 0x7fffu + ((u >> 16) & 1u);   // RNE
  return (unsigned short)(u >> 16);
}

// ---------------------------------------------------------------------------
// Transpose + fp32->bf16 convert: src fp32 [E][R][C] -> dst bf16 [E][C][R]
// ---------------------------------------------------------------------------
__global__ __launch_bounds__(256) void transpose_f32_to_bf16(
    const float* __restrict__ src, unsigned short* __restrict__ dst, int R, int C)
{
  __shared__ float tile[64][65];
  const int e = blockIdx.z;
  const float* s = src + (size_t)e * R * C;
  unsigned short* d = dst + (size_t)e * R * C;
  const int c0 = blockIdx.x * 64, r0 = blockIdx.y * 64;
  const int tx = threadIdx.x & 63;
  const int ty = threadIdx.x >> 6;
#pragma unroll
  for (int i = 0; i < 16; ++i) {
    int r = ty + i * 4;
    tile[r][tx] = s[(size_t)(r0 + r) * C + c0 + tx];
  }
  __syncthreads();
  // write side: ushort2 per thread (2 consecutive output cols = src rows)
  const int rx = (threadIdx.x & 31) * 2;   // 0..62
  const int cy = threadIdx.x >> 5;         // 0..7
#pragma unroll
  for (int i = 0; i < 8; ++i) {
    int c = cy + i * 8;
    ushort2 o;
    o.x = f2bf(tile[rx][c]);
    o.y = f2bf(tile[rx + 1][c]);
    *(ushort2*)&d[(size_t)(c0 + c) * R + r0 + rx] = o;
  }
}

// ---------------------------------------------------------------------------
// Router: logits (fp32 exact), sigmoid, top-2, slot assignment, aux partials
// ---------------------------------------------------------------------------
__global__ __launch_bounds__(256) void router_kernel(
    const float* __restrict__ x, const float* __restrict__ rw,
    const float* __restrict__ rb, int* __restrict__ counts,
    int* __restrict__ expert_of, int* __restrict__ slot_of,
    float* __restrict__ w_of, float* __restrict__ tok_ssq)
{
  const int wave = threadIdx.x >> 6, lane = threadIdx.x & 63;
  const int t = blockIdx.x * 4 + wave;   // one wave per token
  const float4* x4 = (const float4*)(x + (size_t)t * D_);
  const float4* rw4 = (const float4*)rw;
  float acc[E_];
#pragma unroll
  for (int e = 0; e < E_; ++e) acc[e] = 0.f;
#pragma unroll
  for (int d4 = 0; d4 < D_ / 4 / 64; ++d4) {       // 4 iterations
    int idx = d4 * 64 + lane;
    float4 xv = x4[idx];
#pragma unroll
    for (int e = 0; e < E_; ++e) {
      float4 wv = rw4[e * (D_ / 4) + idx];
      acc[e] += xv.x * wv.x + xv.y * wv.y + xv.z * wv.z + xv.w * wv.w;
    }
  }
#pragma unroll
  for (int e = 0; e < E_; ++e) {
    float v = acc[e];
#pragma unroll
    for (int sh = 32; sh > 0; sh >>= 1) v += __shfl_xor(v, sh, 64);
    acc[e] = v;
  }
  if (lane == 0) {
    float logits[E_], sc[E_], ssq = 0.f;
#pragma unroll
    for (int e = 0; e < E_; ++e) {
      logits[e] = acc[e] + rb[e];
      ssq += logits[e] * logits[e];
      sc[e] = 1.f / (1.f + __expf(-logits[e]));
    }
    tok_ssq[t] = ssq;
    int i1 = 0;
#pragma unroll
    for (int e = 1; e < E_; ++e) if (sc[e] > sc[i1]) i1 = e;     // ties -> low idx
    int i2 = (i1 == 0) ? 1 : 0;
#pragma unroll
    for (int e = 0; e < E_; ++e)
      if (e != i1 && e != i2 && sc[e] > sc[i2]) i2 = e;
    float v1 = sc[i1], v2 = sc[i2];
    float inv = 1.f / (v1 + v2 + 1e-6f);
    int s1 = atomicAdd(&counts[i1], 1);
    int s2 = atomicAdd(&counts[i2], 1);
    expert_of[t * 2]     = i1; slot_of[t * 2]     = s1; w_of[t * 2]     = v1 * inv;
    expert_of[t * 2 + 1] = i2; slot_of[t * 2 + 1] = s2; w_of[t * 2 + 1] = v2 * inv;
  }
}

// offsets + compacted tile table (load balancing: dead tiles at the tail)
__global__ void offsets_kernel(const int* __restrict__ counts, int* __restrict__ offsets,
                               int* __restrict__ tile_e, int* __restrict__ tile_m0)
{
  if (threadIdx.x == 0) {
    int o = 0, nt = 0;
    for (int e = 0; e < E_; ++e) {
      offsets[e] = o;
      for (int m0 = 0; m0 < counts[e]; m0 += 128) {
        tile_e[nt] = e; tile_m0[nt] = m0; ++nt;
      }
      o += counts[e];
    }
    for (; nt < MAXTILES_; ++nt) tile_e[nt] = -1;
  }
}

__global__ __launch_bounds__(256) void aux_kernel(const float* __restrict__ tok_ssq,
                                                  float* __restrict__ out_aux)
{
  __shared__ float sm[256];
  float s = 0.f;
  for (int i = threadIdx.x; i < TOK_; i += 256) s += tok_ssq[i];
  sm[threadIdx.x] = s;
  __syncthreads();
  for (int h = 128; h > 0; h >>= 1) {
    if (threadIdx.x < h) sm[threadIdx.x] += sm[threadIdx.x + h];
    __syncthreads();
  }
  if (threadIdx.x == 0) *out_aux = 0.01f * sm[0] / (float)(TOK_ * E_);
}

// ---------------------------------------------------------------------------
// Pack: gather selected token rows (fp32 -> bf16) into compacted A matrix
// ---------------------------------------------------------------------------
__global__ __launch_bounds__(256) void pack_kernel(
    const float* __restrict__ x, const int* __restrict__ expert_of,
    const int* __restrict__ slot_of, const float* __restrict__ w_of,
    const int* __restrict__ offsets, unsigned short* __restrict__ px,
    int* __restrict__ tok_ids, float* __restrict__ tok_w)
{
  const int pair = blockIdx.x;
  const int t = pair >> 1;
  const int e = expert_of[pair];
  const int row = offsets[e] + slot_of[pair];
  if (threadIdx.x == 0) { tok_ids[row] = t; tok_w[row] = w_of[pair]; }
  const float4* xr = (const float4*)(x + (size_t)t * D_);
  ushort4* pr = (ushort4*)(px + (size_t)row * D_);
  float4 v = xr[threadIdx.x];              // 256 threads x 4 = 1024 elems
  ushort4 o;
  o.x = f2bf(v.x); o.y = f2bf(v.y); o.z = f2bf(v.z); o.w = f2bf(v.w);
  pr[threadIdx.x] = o;
}

// ---------------------------------------------------------------------------
// GEMM staging: 128-row x 32-col bf16 tile via global_load_lds width-16.
// LDS layout [row][seg], with XOR swizzle: LDS[row][s] = G[row][s ^ g(row)],
// g(row) = (row>>1)&3  -> frag reads are 2-way-aliased max (free).
// ---------------------------------------------------------------------------
__device__ __forceinline__ void stage_tile(const unsigned short* gbase, int gstride,
                                           unsigned short* sbase, int kk,
                                           int wave, int lane)
{
  const int seg = (lane & 3) ^ ((lane >> 3) & 3);   // g(row)=(localrow>>1)&3
#pragma unroll
  for (int c = 0; c < 2; ++c) {
    const unsigned short* g = gbase
        + (size_t)(wave * 32 + c * 16 + (lane >> 2)) * gstride + kk + seg * 8;
    unsigned short* s = sbase + (wave * 32 + c * 16) * 32;   // wave-uniform base
    __builtin_amdgcn_global_load_lds(
        (const __attribute__((address_space(1))) void*)g,
        (__attribute__((address_space(3))) void*)s, 16, 0, 0);
  }
}

// A-staging with row clamp (avoids OOB reads past the packed matrix end)
__device__ __forceinline__ void stage_tile_clamped(const unsigned short* gbase, int gstride,
                                                   int row0, int rowmax,
                                                   unsigned short* sbase, int kk,
                                                   int wave, int lane)
{
  const int seg = (lane & 3) ^ ((lane >> 3) & 3);
#pragma unroll
  for (int c = 0; c < 2; ++c) {
    int r = row0 + wave * 32 + c * 16 + (lane >> 2);
    r = (r < rowmax) ? r : rowmax - 1;
    const unsigned short* g = gbase + (size_t)r * gstride + kk + seg * 8;
    unsigned short* s = sbase + (wave * 32 + c * 16) * 32;
    __builtin_amdgcn_global_load_lds(
        (const __attribute__((address_space(1))) void*)g,
        (__attribute__((address_space(3))) void*)s, 16, 0, 0);
  }
}

__device__ __forceinline__ short8 read_frag(const unsigned short* smem, int row, int lk) {
  const int s = lk ^ ((row >> 1) & 3);
  return *(const short8*)&smem[row * 32 + s * 8];
}

// ---------------------------------------------------------------------------
// GEMM1 + fused SwiGLU: hid[row][h] = silu(px@w1)[row][h] * (px@w2)[row][h]
// Block: 128 rows x 128 hidden cols (paired tiles h and h+2048). 4 waves 2x2.
// ---------------------------------------------------------------------------
__global__ __launch_bounds__(256, 2) void gemm1_kernel(
    const unsigned short* __restrict__ px, const unsigned short* __restrict__ w12t,
    unsigned short* __restrict__ hid, const int* __restrict__ counts,
    const int* __restrict__ offsets, const int* __restrict__ tile_e,
    const int* __restrict__ tile_m0)
{
  const int ti = blockIdx.y, nt = blockIdx.x;
  const int e = tile_e[ti];
  if (e < 0) return;
  const int m0 = tile_m0[ti];
  const int cnt = counts[e];
  const int off = offsets[e];
  const int tid = threadIdx.x;
  const int wave = tid >> 6, lane = tid & 63;
  const int wm = wave >> 1, wn = wave & 1;
  const int lr = lane & 15, lk = lane >> 4;

  __shared__ __align__(16) unsigned short As[128 * 32];
  __shared__ __align__(16) unsigned short B1s[128 * 32];
  __shared__ __align__(16) unsigned short B2s[128 * 32];

  f32x4 zero = {0.f, 0.f, 0.f, 0.f};
  f32x4 acc1[4][4], acc2[4][4];
#pragma unroll
  for (int mi = 0; mi < 4; ++mi)
#pragma unroll
    for (int ni = 0; ni < 4; ++ni) { acc1[mi][ni] = zero; acc2[mi][ni] = zero; }

  const unsigned short* B1base = w12t + ((size_t)e * N1_ + nt * 128) * D_;
  const unsigned short* B2base = w12t + ((size_t)e * N1_ + H_ + nt * 128) * D_;

  for (int kk = 0; kk < D_; kk += 32) {
    stage_tile_clamped(px, D_, off + m0, PAIRS_, As, kk, wave, lane);
    stage_tile(B1base, D_, B1s, kk, wave, lane);
    stage_tile(B2base, D_, B2s, kk, wave, lane);
    __syncthreads();
    short8 a[4], b1[4], b2[4];
#pragma unroll
    for (int i = 0; i < 4; ++i) {
      a[i]  = read_frag(As,  wm * 64 + i * 16 + lr, lk);
      b1[i] = read_frag(B1s, wn * 64 + i * 16 + lr, lk);
      b2[i] = read_frag(B2s, wn * 64 + i * 16 + lr, lk);
    }
#pragma unroll
    for (int mi = 0; mi < 4; ++mi)
#pragma unroll
      for (int ni = 0; ni < 4; ++ni) {
        acc1[mi][ni] = __builtin_amdgcn_mfma_f32_16x16x32_bf16(a[mi], b1[ni], acc1[mi][ni], 0, 0, 0);
        acc2[mi][ni] = __builtin_amdgcn_mfma_f32_16x16x32_bf16(a[mi], b2[ni], acc2[mi][ni], 0, 0, 0);
      }
    __syncthreads();
  }

  // epilogue: SwiGLU + bf16 store (C/D layout: col=lane&15, row=(lane>>4)*4+r)
#pragma unroll
  for (int mi = 0; mi < 4; ++mi)
#pragma unroll
    for (int r = 0; r < 4; ++r) {
      int row_local = m0 + wm * 64 + mi * 16 + lk * 4 + r;
      if (row_local < cnt) {
#pragma unroll
        for (int ni = 0; ni < 4; ++ni) {
          int col = nt * 128 + wn * 64 + ni * 16 + lr;
          float v1 = acc1[mi][ni][r];
          float v2 = acc2[mi][ni][r];
          float hval = (v1 / (1.f + __expf(-v1))) * v2;
          hid[(size_t)(off + row_local) * H_ + col] = f2bf(hval);
        }
      }
    }
}

// ---------------------------------------------------------------------------
// GEMM2: out[tok] += weight * (hid @ w3t^T), split-K=2 via fp32 atomics
// ---------------------------------------------------------------------------
__global__ __launch_bounds__(256, 4) void gemm2_kernel(
    const unsigned short* __restrict__ hid, const unsigned short* __restrict__ w3t,
    const int* __restrict__ counts, const int* __restrict__ offsets,
    const int* __restrict__ tile_e, const int* __restrict__ tile_m0,
    const int* __restrict__ tok_ids, const float* __restrict__ tok_w,
    float* __restrict__ out)
{
  const int ti = blockIdx.y, nt = blockIdx.x, ks = blockIdx.z;
  const int e = tile_e[ti];
  if (e < 0) return;
  const int m0 = tile_m0[ti];
  const int cnt = counts[e];
  const int off = offsets[e];
  const int tid = threadIdx.x;
  const int wave = tid >> 6, lane = tid & 63;
  const int wm = wave >> 1, wn = wave & 1;
  const int lr = lane & 15, lk = lane >> 4;

  __shared__ __align__(16) unsigned short As[128 * 32];
  __shared__ __align__(16) unsigned short Bs[128 * 32];

  f32x4 zero = {0.f, 0.f, 0.f, 0.f};
  f32x4 acc[4][4];
#pragma unroll
  for (int mi = 0; mi < 4; ++mi)
#pragma unroll
    for (int ni = 0; ni < 4; ++ni) acc[mi][ni] = zero;

  const unsigned short* Bbase = w3t + ((size_t)e * D_ + nt * 128) * H_;

  const int k0 = ks * (H_ / 2), k1 = k0 + (H_ / 2);
  for (int kk = k0; kk < k1; kk += 32) {
    stage_tile_clamped(hid, H_, off + m0, PAIRS_, As, kk, wave, lane);
    stage_tile(Bbase, H_, Bs, kk, wave, lane);
    __syncthreads();
    short8 a[4], b[4];
#pragma unroll
    for (int i = 0; i < 4; ++i) {
      a[i] = read_frag(As, wm * 64 + i * 16 + lr, lk);
      b[i] = read_frag(Bs, wn * 64 + i * 16 + lr, lk);
    }
#pragma unroll
    for (int mi = 0; mi < 4; ++mi)
#pragma unroll
      for (int ni = 0; ni < 4; ++ni)
        acc[mi][ni] = __builtin_amdgcn_mfma_f32_16x16x32_bf16(a[mi], b[ni], acc[mi][ni], 0, 0, 0);
    __syncthreads();
  }

#pragma unroll
  for (int mi = 0; mi < 4; ++mi)
#pragma unroll
    for (int r = 0; r < 4; ++r) {
      int row_local = m0 + wm * 64 + mi * 16 + lk * 4 + r;
      if (row_local < cnt) {
        int g = off + row_local;
        int t = tok_ids[g];
        float wgt = tok_w[g];
#pragma unroll
        for (int ni = 0; ni < 4; ++ni) {
          int col = nt * 128 + wn * 64 + ni * 16 + lr;
          atomicAdd(&out[(size_t)t * D_ + col], acc[mi][ni][r] * wgt);
        }
      }
    }
}

// ---------------------------------------------------------------------------
extern "C" void kernel_launch(void* const* d_in, const int* in_sizes, int n_in,
                              void* d_out, int out_size, void* d_ws, size_t ws_size,
                              hipStream_t stream)
{
  const float* x   = (const float*)d_in[0];
  const float* rw  = (const float*)d_in[1];
  const float* rb  = (const float*)d_in[2];
  const float* w12 = (const float*)d_in[3];
  const float* w3  = (const float*)d_in[4];
  float* out = (float*)d_out;

  // workspace layout (~120.1 MB total)
  char* wsb = (char*)d_ws;
  int*   counts    = (int*)(wsb + 0);                 // 8 ints
  int*   offsets   = (int*)(wsb + 64);                // 8 ints
  int*   tile_e    = (int*)(wsb + 128);               // 40 ints
  int*   tile_m0   = (int*)(wsb + 384);               // 40 ints
  int*   expert_of = (int*)(wsb + 1024);              // 4096 ints
  int*   slot_of   = (int*)(wsb + 1024 + 16384);
  float* w_of      = (float*)(wsb + 1024 + 2 * 16384);
  int*   tok_ids   = (int*)(wsb + 1024 + 3 * 16384);
  float* tok_w     = (float*)(wsb + 1024 + 4 * 16384);
  float* tok_ssq   = (float*)(wsb + 1024 + 5 * 16384);        // 2048 floats
  unsigned short* px   = (unsigned short*)(wsb + (128 << 10));                          // 8 MB
  unsigned short* hid  = (unsigned short*)(wsb + (128 << 10) + ((size_t)8  << 20));     // 16 MB
  unsigned short* w12t = (unsigned short*)(wsb + (128 << 10) + ((size_t)24 << 20));     // 64 MB
  unsigned short* w3t  = (unsigned short*)(wsb + (128 << 10) + ((size_t)88 << 20));     // 32 MB

  hipMemsetAsync(counts, 0, E_ * sizeof(int), stream);
  hipMemsetAsync(out, 0, (size_t)out_size * sizeof(float), stream);

  transpose_f32_to_bf16<<<dim3(N1_ / 64, D_ / 64, E_), 256, 0, stream>>>(w12, w12t, D_, N1_);
  transpose_f32_to_bf16<<<dim3(D_ / 64, H_ / 64, E_), 256, 0, stream>>>(w3, w3t, H_, D_);
  router_kernel<<<TOK_ / 4, 256, 0, stream>>>(x, rw, rb, counts, expert_of, slot_of, w_of, tok_ssq);
  offsets_kernel<<<1, 64, 0, stream>>>(counts, offsets, tile_e, tile_m0);
  aux_kernel<<<1, 256, 0, stream>>>(tok_ssq, out + (size_t)TOK_ * D_);
  pack_kernel<<<PAIRS_, 256, 0, stream>>>(x, expert_of, slot_of, w_of, offsets, px, tok_ids, tok_w);
  gemm1_kernel<<<dim3(16, MAXTILES_), 256, 0, stream>>>(px, w12t, hid, counts, offsets, tile_e, tile_m0);
  gemm2_kernel<<<dim3(8, MAXTILES_, 2), 256, 0, stream>>>(hid, w3t, counts, offsets, tile_e, tile_m0, tok_ids, tok_w, out);
}

// Round 3
// 431.037 us; speedup vs baseline: 1.1346x; 1.0340x over previous
//
#include <hip/hip_runtime.h>
#include <math.h>
#include <stdint.h>

#define B_ 2
#define S_ 1024
#define D_ 1024
#define H_ 2048
#define E_ 8
#define TOK_ (B_*S_)      // 2048 tokens
#define N1_ (2*H_)        // 4096
#define PAIRS_ (TOK_*2)   // 4096 (token, expert-slot) pairs
#define MAXTILES_ 40      // max sum of ceil(cnt_e/128) = 32 + 7

typedef float f32x4 __attribute__((ext_vector_type(4)));
typedef short short8 __attribute__((ext_vector_type(8)));

__device__ __forceinline__ unsigned short f2bf(float f) {
  unsigned int u = __float_as_uint(f);
  u += 0x7fffu + ((u >> 16) & 1u);   // RNE
  return (unsigned short)(u >> 16);
}

// ---------------------------------------------------------------------------
// Transpose + fp32->bf16 convert: src fp32 [E][R][C] -> dst bf16 [E][C][R]
// ---------------------------------------------------------------------------
__global__ __launch_bounds__(256) void transpose_f32_to_bf16(
    const float* __restrict__ src, unsigned short* __restrict__ dst, int R, int C)
{
  __shared__ float tile[64][65];
  const int e = blockIdx.z;
  const float* s = src + (size_t)e * R * C;
  unsigned short* d = dst + (size_t)e * R * C;
  const int c0 = blockIdx.x * 64, r0 = blockIdx.y * 64;
  const int tx = threadIdx.x & 63;
  const int ty = threadIdx.x >> 6;
#pragma unroll
  for (int i = 0; i < 16; ++i) {
    int r = ty + i * 4;
    tile[r][tx] = s[(size_t)(r0 + r) * C + c0 + tx];
  }
  __syncthreads();
  // write side: ushort2 per thread (2 consecutive output cols = src rows)
  const int rx = (threadIdx.x & 31) * 2;   // 0..62
  const int cy = threadIdx.x >> 5;         // 0..7
#pragma unroll
  for (int i = 0; i < 8; ++i) {
    int c = cy + i * 8;
    ushort2 o;
    o.x = f2bf(tile[rx][c]);
    o.y = f2bf(tile[rx + 1][c]);
    *(ushort2*)&d[(size_t)(c0 + c) * R + r0 + rx] = o;
  }
}

// ---------------------------------------------------------------------------
// Router: logits (fp32 exact), sigmoid, top-2, slot assignment, aux partials
// ---------------------------------------------------------------------------
__global__ __launch_bounds__(256) void router_kernel(
    const float* __restrict__ x, const float* __restrict__ rw,
    const float* __restrict__ rb, int* __restrict__ counts,
    int* __restrict__ expert_of, int* __restrict__ slot_of,
    float* __restrict__ w_of, float* __restrict__ tok_ssq)
{
  const int wave = threadIdx.x >> 6, lane = threadIdx.x & 63;
  const int t = blockIdx.x * 4 + wave;   // one wave per token
  const float4* x4 = (const float4*)(x + (size_t)t * D_);
  const float4* rw4 = (const float4*)rw;
  float acc[E_];
#pragma unroll
  for (int e = 0; e < E_; ++e) acc[e] = 0.f;
#pragma unroll
  for (int d4 = 0; d4 < D_ / 4 / 64; ++d4) {       // 4 iterations
    int idx = d4 * 64 + lane;
    float4 xv = x4[idx];
#pragma unroll
    for (int e = 0; e < E_; ++e) {
      float4 wv = rw4[e * (D_ / 4) + idx];
      acc[e] += xv.x * wv.x + xv.y * wv.y + xv.z * wv.z + xv.w * wv.w;
    }
  }
#pragma unroll
  for (int e = 0; e < E_; ++e) {
    float v = acc[e];
#pragma unroll
    for (int sh = 32; sh > 0; sh >>= 1) v += __shfl_xor(v, sh, 64);
    acc[e] = v;
  }
  if (lane == 0) {
    float logits[E_], sc[E_], ssq = 0.f;
#pragma unroll
    for (int e = 0; e < E_; ++e) {
      logits[e] = acc[e] + rb[e];
      ssq += logits[e] * logits[e];
      sc[e] = 1.f / (1.f + __expf(-logits[e]));
    }
    tok_ssq[t] = ssq;
    int i1 = 0;
#pragma unroll
    for (int e = 1; e < E_; ++e) if (sc[e] > sc[i1]) i1 = e;     // ties -> low idx
    int i2 = (i1 == 0) ? 1 : 0;
#pragma unroll
    for (int e = 0; e < E_; ++e)
      if (e != i1 && e != i2 && sc[e] > sc[i2]) i2 = e;
    float v1 = sc[i1], v2 = sc[i2];
    float inv = 1.f / (v1 + v2 + 1e-6f);
    int s1 = atomicAdd(&counts[i1], 1);
    int s2 = atomicAdd(&counts[i2], 1);
    expert_of[t * 2]     = i1; slot_of[t * 2]     = s1; w_of[t * 2]     = v1 * inv;
    expert_of[t * 2 + 1] = i2; slot_of[t * 2 + 1] = s2; w_of[t * 2 + 1] = v2 * inv;
  }
}

// meta: offsets + compacted tile table (thread 0) + aux-loss reduction (all)
__global__ __launch_bounds__(256) void meta_kernel(
    const int* __restrict__ counts, const float* __restrict__ tok_ssq,
    int* __restrict__ offsets, int* __restrict__ tile_e, int* __restrict__ tile_m0,
    float* __restrict__ out_aux)
{
  if (threadIdx.x == 0) {
    int o = 0, nt = 0;
    for (int e = 0; e < E_; ++e) {
      offsets[e] = o;
      for (int m0 = 0; m0 < counts[e]; m0 += 128) {
        tile_e[nt] = e; tile_m0[nt] = m0; ++nt;
      }
      o += counts[e];
    }
    for (; nt < MAXTILES_; ++nt) tile_e[nt] = -1;
  }
  __shared__ float sm[256];
  float s = 0.f;
  for (int i = threadIdx.x; i < TOK_; i += 256) s += tok_ssq[i];
  sm[threadIdx.x] = s;
  __syncthreads();
  for (int h = 128; h > 0; h >>= 1) {
    if (threadIdx.x < h) sm[threadIdx.x] += sm[threadIdx.x + h];
    __syncthreads();
  }
  if (threadIdx.x == 0) *out_aux = 0.01f * sm[0] / (float)(TOK_ * E_);
}

// ---------------------------------------------------------------------------
// Pack: gather selected token rows (fp32 -> bf16) into compacted A matrix
// ---------------------------------------------------------------------------
__global__ __launch_bounds__(256) void pack_kernel(
    const float* __restrict__ x, const int* __restrict__ expert_of,
    const int* __restrict__ slot_of, const int* __restrict__ offsets,
    unsigned short* __restrict__ px, int* __restrict__ pair_row)
{
  const int pair = blockIdx.x;
  const int t = pair >> 1;
  const int e = expert_of[pair];
  const int row = offsets[e] + slot_of[pair];
  if (threadIdx.x == 0) pair_row[pair] = row;
  const float4* xr = (const float4*)(x + (size_t)t * D_);
  ushort4* pr = (ushort4*)(px + (size_t)row * D_);
  float4 v = xr[threadIdx.x];              // 256 threads x 4 = 1024 elems
  ushort4 o;
  o.x = f2bf(v.x); o.y = f2bf(v.y); o.z = f2bf(v.z); o.w = f2bf(v.w);
  pr[threadIdx.x] = o;
}

// ---------------------------------------------------------------------------
// GEMM staging: 128-row x 32-col bf16 tile via global_load_lds width-16.
// LDS layout [row][seg], with XOR swizzle: LDS[row][s] = G[row][s ^ g(row)],
// g(row) = (row>>1)&3  -> frag reads are 2-way-aliased max (free).
// ---------------------------------------------------------------------------
__device__ __forceinline__ void stage_tile(const unsigned short* gbase, int gstride,
                                           unsigned short* sbase, int kk,
                                           int wave, int lane)
{
  const int seg = (lane & 3) ^ ((lane >> 3) & 3);   // g(row)=(localrow>>1)&3
#pragma unroll
  for (int c = 0; c < 2; ++c) {
    const unsigned short* g = gbase
        + (size_t)(wave * 32 + c * 16 + (lane >> 2)) * gstride + kk + seg * 8;
    unsigned short* s = sbase + (wave * 32 + c * 16) * 32;   // wave-uniform base
    __builtin_amdgcn_global_load_lds(
        (const __attribute__((address_space(1))) void*)g,
        (__attribute__((address_space(3))) void*)s, 16, 0, 0);
  }
}

// A-staging with row clamp (avoids OOB reads past the packed matrix end)
__device__ __forceinline__ void stage_tile_clamped(const unsigned short* gbase, int gstride,
                                                   int row0, int rowmax,
                                                   unsigned short* sbase, int kk,
                                                   int wave, int lane)
{
  const int seg = (lane & 3) ^ ((lane >> 3) & 3);
#pragma unroll
  for (int c = 0; c < 2; ++c) {
    int r = row0 + wave * 32 + c * 16 + (lane >> 2);
    r = (r < rowmax) ? r : rowmax - 1;
    const unsigned short* g = gbase + (size_t)r * gstride + kk + seg * 8;
    unsigned short* s = sbase + (wave * 32 + c * 16) * 32;
    __builtin_amdgcn_global_load_lds(
        (const __attribute__((address_space(1))) void*)g,
        (__attribute__((address_space(3))) void*)s, 16, 0, 0);
  }
}

__device__ __forceinline__ short8 read_frag(const unsigned short* smem, int row, int lk) {
  const int s = lk ^ ((row >> 1) & 3);
  return *(const short8*)&smem[row * 32 + s * 8];
}

// ---------------------------------------------------------------------------
// GEMM1 + fused SwiGLU: hid[row][h] = silu(px@w1)[row][h] * (px@w2)[row][h]
// Block: 128 rows x 128 hidden cols (paired tiles h and h+2048). 4 waves 2x2.
// ---------------------------------------------------------------------------
__global__ __launch_bounds__(256, 2) void gemm1_kernel(
    const unsigned short* __restrict__ px, const unsigned short* __restrict__ w12t,
    unsigned short* __restrict__ hid, const int* __restrict__ counts,
    const int* __restrict__ offsets, const int* __restrict__ tile_e,
    const int* __restrict__ tile_m0)
{
  const int ti = blockIdx.y, nt = blockIdx.x;
  const int e = tile_e[ti];
  if (e < 0) return;
  const int m0 = tile_m0[ti];
  const int cnt = counts[e];
  const int off = offsets[e];
  const int tid = threadIdx.x;
  const int wave = tid >> 6, lane = tid & 63;
  const int wm = wave >> 1, wn = wave & 1;
  const int lr = lane & 15, lk = lane >> 4;

  __shared__ __align__(16) unsigned short As[128 * 32];
  __shared__ __align__(16) unsigned short B1s[128 * 32];
  __shared__ __align__(16) unsigned short B2s[128 * 32];

  f32x4 zero = {0.f, 0.f, 0.f, 0.f};
  f32x4 acc1[4][4], acc2[4][4];
#pragma unroll
  for (int mi = 0; mi < 4; ++mi)
#pragma unroll
    for (int ni = 0; ni < 4; ++ni) { acc1[mi][ni] = zero; acc2[mi][ni] = zero; }

  const unsigned short* B1base = w12t + ((size_t)e * N1_ + nt * 128) * D_;
  const unsigned short* B2base = w12t + ((size_t)e * N1_ + H_ + nt * 128) * D_;

  for (int kk = 0; kk < D_; kk += 32) {
    stage_tile_clamped(px, D_, off + m0, PAIRS_, As, kk, wave, lane);
    stage_tile(B1base, D_, B1s, kk, wave, lane);
    stage_tile(B2base, D_, B2s, kk, wave, lane);
    __syncthreads();
    short8 a[4], b1[4], b2[4];
#pragma unroll
    for (int i = 0; i < 4; ++i) {
      a[i]  = read_frag(As,  wm * 64 + i * 16 + lr, lk);
      b1[i] = read_frag(B1s, wn * 64 + i * 16 + lr, lk);
      b2[i] = read_frag(B2s, wn * 64 + i * 16 + lr, lk);
    }
#pragma unroll
    for (int mi = 0; mi < 4; ++mi)
#pragma unroll
      for (int ni = 0; ni < 4; ++ni) {
        acc1[mi][ni] = __builtin_amdgcn_mfma_f32_16x16x32_bf16(a[mi], b1[ni], acc1[mi][ni], 0, 0, 0);
        acc2[mi][ni] = __builtin_amdgcn_mfma_f32_16x16x32_bf16(a[mi], b2[ni], acc2[mi][ni], 0, 0, 0);
      }
    __syncthreads();
  }

  // epilogue: SwiGLU + bf16 store (C/D layout: col=lane&15, row=(lane>>4)*4+r)
#pragma unroll
  for (int mi = 0; mi < 4; ++mi)
#pragma unroll
    for (int r = 0; r < 4; ++r) {
      int row_local = m0 + wm * 64 + mi * 16 + lk * 4 + r;
      if (row_local < cnt) {
#pragma unroll
        for (int ni = 0; ni < 4; ++ni) {
          int col = nt * 128 + wn * 64 + ni * 16 + lr;
          float v1 = acc1[mi][ni][r];
          float v2 = acc2[mi][ni][r];
          float hval = (v1 / (1.f + __expf(-v1))) * v2;
          hid[(size_t)(off + row_local) * H_ + col] = f2bf(hval);
        }
      }
    }
}

// ---------------------------------------------------------------------------
// GEMM2: ybuf[ks][row][d] = (hid @ w3t^T) over K-half ks.  Plain stores.
// ---------------------------------------------------------------------------
__global__ __launch_bounds__(256, 4) void gemm2_kernel(
    const unsigned short* __restrict__ hid, const unsigned short* __restrict__ w3t,
    const int* __restrict__ counts, const int* __restrict__ offsets,
    const int* __restrict__ tile_e, const int* __restrict__ tile_m0,
    float* __restrict__ ybuf)
{
  const int ti = blockIdx.y, nt = blockIdx.x, ks = blockIdx.z;
  const int e = tile_e[ti];
  if (e < 0) return;
  const int m0 = tile_m0[ti];
  const int cnt = counts[e];
  const int off = offsets[e];
  const int tid = threadIdx.x;
  const int wave = tid >> 6, lane = tid & 63;
  const int wm = wave >> 1, wn = wave & 1;
  const int lr = lane & 15, lk = lane >> 4;

  __shared__ __align__(16) unsigned short As[128 * 32];
  __shared__ __align__(16) unsigned short Bs[128 * 32];

  f32x4 zero = {0.f, 0.f, 0.f, 0.f};
  f32x4 acc[4][4];
#pragma unroll
  for (int mi = 0; mi < 4; ++mi)
#pragma unroll
    for (int ni = 0; ni < 4; ++ni) acc[mi][ni] = zero;

  const unsigned short* Bbase = w3t + ((size_t)e * D_ + nt * 128) * H_;
  float* yb = ybuf + (size_t)ks * PAIRS_ * D_;

  const int k0 = ks * (H_ / 2), k1 = k0 + (H_ / 2);
  for (int kk = k0; kk < k1; kk += 32) {
    stage_tile_clamped(hid, H_, off + m0, PAIRS_, As, kk, wave, lane);
    stage_tile(Bbase, H_, Bs, kk, wave, lane);
    __syncthreads();
    short8 a[4], b[4];
#pragma unroll
    for (int i = 0; i < 4; ++i) {
      a[i] = read_frag(As, wm * 64 + i * 16 + lr, lk);
      b[i] = read_frag(Bs, wn * 64 + i * 16 + lr, lk);
    }
#pragma unroll
    for (int mi = 0; mi < 4; ++mi)
#pragma unroll
      for (int ni = 0; ni < 4; ++ni)
        acc[mi][ni] = __builtin_amdgcn_mfma_f32_16x16x32_bf16(a[mi], b[ni], acc[mi][ni], 0, 0, 0);
    __syncthreads();
  }

#pragma unroll
  for (int mi = 0; mi < 4; ++mi)
#pragma unroll
    for (int r = 0; r < 4; ++r) {
      int row_local = m0 + wm * 64 + mi * 16 + lk * 4 + r;
      if (row_local < cnt) {
        int g = off + row_local;
#pragma unroll
        for (int ni = 0; ni < 4; ++ni) {
          int col = nt * 128 + wn * 64 + ni * 16 + lr;
          yb[(size_t)g * D_ + col] = acc[mi][ni][r];
        }
      }
    }
}

// ---------------------------------------------------------------------------
// Combine: out[t][d] = w0*(y0[r0][d]+y1[r0][d]) + w1*(y0[r1][d]+y1[r1][d])
// ---------------------------------------------------------------------------
__global__ __launch_bounds__(256) void combine_kernel(
    const float* __restrict__ ybuf, const int* __restrict__ pair_row,
    const float* __restrict__ w_of, float* __restrict__ out)
{
  const int t = blockIdx.x;
  const int r0 = pair_row[t * 2], r1 = pair_row[t * 2 + 1];
  const float w0 = w_of[t * 2], w1 = w_of[t * 2 + 1];
  const float4* y0 = (const float4*)(ybuf);
  const float4* y1 = (const float4*)(ybuf + (size_t)PAIRS_ * D_);
  const int i = threadIdx.x;
  float4 a0 = y0[(size_t)r0 * (D_ / 4) + i];
  float4 b0 = y1[(size_t)r0 * (D_ / 4) + i];
  float4 a1 = y0[(size_t)r1 * (D_ / 4) + i];
  float4 b1 = y1[(size_t)r1 * (D_ / 4) + i];
  float4 o;
  o.x = w0 * (a0.x + b0.x) + w1 * (a1.x + b1.x);
  o.y = w0 * (a0.y + b0.y) + w1 * (a1.y + b1.y);
  o.z = w0 * (a0.z + b0.z) + w1 * (a1.z + b1.z);
  o.w = w0 * (a0.w + b0.w) + w1 * (a1.w + b1.w);
  ((float4*)out)[(size_t)t * (D_ / 4) + i] = o;
}

// ---------------------------------------------------------------------------
extern "C" void kernel_launch(void* const* d_in, const int* in_sizes, int n_in,
                              void* d_out, int out_size, void* d_ws, size_t ws_size,
                              hipStream_t stream)
{
  const float* x   = (const float*)d_in[0];
  const float* rw  = (const float*)d_in[1];
  const float* rb  = (const float*)d_in[2];
  const float* w12 = (const float*)d_in[3];
  const float* w3  = (const float*)d_in[4];
  float* out = (float*)d_out;

  // workspace layout (~152.1 MB total)
  char* wsb = (char*)d_ws;
  int*   counts    = (int*)(wsb + 0);                 // 8 ints
  int*   offsets   = (int*)(wsb + 64);                // 8 ints
  int*   tile_e    = (int*)(wsb + 128);               // 40 ints
  int*   tile_m0   = (int*)(wsb + 384);               // 40 ints
  int*   expert_of = (int*)(wsb + 1024);              // 4096 ints
  int*   slot_of   = (int*)(wsb + 1024 + 16384);
  float* w_of      = (float*)(wsb + 1024 + 2 * 16384);
  int*   pair_row  = (int*)(wsb + 1024 + 3 * 16384);
  float* tok_ssq   = (float*)(wsb + 1024 + 4 * 16384);        // 2048 floats
  unsigned short* px   = (unsigned short*)(wsb + (128 << 10));                          // 8 MB
  unsigned short* hid  = (unsigned short*)(wsb + (128 << 10) + ((size_t)8  << 20));     // 16 MB
  unsigned short* w12t = (unsigned short*)(wsb + (128 << 10) + ((size_t)24 << 20));     // 64 MB
  unsigned short* w3t  = (unsigned short*)(wsb + (128 << 10) + ((size_t)88 << 20));     // 32 MB
  float*          ybuf = (float*)(wsb + (128 << 10) + ((size_t)120 << 20));             // 32 MB

  hipMemsetAsync(counts, 0, E_ * sizeof(int), stream);

  transpose_f32_to_bf16<<<dim3(N1_ / 64, D_ / 64, E_), 256, 0, stream>>>(w12, w12t, D_, N1_);
  transpose_f32_to_bf16<<<dim3(D_ / 64, H_ / 64, E_), 256, 0, stream>>>(w3, w3t, H_, D_);
  router_kernel<<<TOK_ / 4, 256, 0, stream>>>(x, rw, rb, counts, expert_of, slot_of, w_of, tok_ssq);
  meta_kernel<<<1, 256, 0, stream>>>(counts, tok_ssq, offsets, tile_e, tile_m0, out + (size_t)TOK_ * D_);
  pack_kernel<<<PAIRS_, 256, 0, stream>>>(x, expert_of, slot_of, offsets, px, pair_row);
  gemm1_kernel<<<dim3(16, MAXTILES_), 256, 0, stream>>>(px, w12t, hid, counts, offsets, tile_e, tile_m0);
  gemm2_kernel<<<dim3(8, MAXTILES_, 2), 256, 0, stream>>>(hid, w3t, counts, offsets, tile_e, tile_m0, ybuf);
  combine_kernel<<<TOK_, 256, 0, stream>>>(ybuf, pair_row, w_of, out);
}

// Round 4
// 417.139 us; speedup vs baseline: 1.1724x; 1.0333x over previous
//
#include <hip/hip_runtime.h>
#include <math.h>
#include <stdint.h>

#define B_ 2
#define S_ 1024
#define D_ 1024
#define H_ 2048
#define E_ 8
#define TOK_ (B_*S_)      // 2048 tokens
#define N1_ (2*H_)        // 4096
#define PAIRS_ (TOK_*2)   // 4096 (token, expert-slot) pairs
#define MAXTILES_ 40      // max sum of ceil(cnt_e/128) = 32 + 7

typedef float f32x4 __attribute__((ext_vector_type(4)));
typedef short short8 __attribute__((ext_vector_type(8)));

__device__ __forceinline__ unsigned short f2bf(float f) {
  unsigned int u = __float_as_uint(f);
  u += 0x7fffu + ((u >> 16) & 1u);   // RNE
  return (unsigned short)(u >> 16);
}
__device__ __forceinline__ float bf2f(unsigned short u) {
  return __uint_as_float(((unsigned int)u) << 16);
}

// ---------------------------------------------------------------------------
// Transpose + fp32->bf16 convert: src fp32 [E][R][C] -> dst bf16 [E][C][R]
// float4 global loads, ushort4 global stores, conflict-free via [65] pad.
// ---------------------------------------------------------------------------
__global__ __launch_bounds__(256) void transpose_f32_to_bf16(
    const float* __restrict__ src, unsigned short* __restrict__ dst, int R, int C)
{
  __shared__ float tile[64][65];
  const int e = blockIdx.z;
  const float* s = src + (size_t)e * R * C;
  unsigned short* d = dst + (size_t)e * R * C;
  const int c0 = blockIdx.x * 64, r0 = blockIdx.y * 64;
  const int lrow = threadIdx.x >> 4;   // 0..15
  const int lc4  = threadIdx.x & 15;   // 0..15
#pragma unroll
  for (int i = 0; i < 4; ++i) {
    int r = lrow + i * 16;
    float4 v = *(const float4*)&s[(size_t)(r0 + r) * C + c0 + lc4 * 4];
    tile[r][lc4 * 4 + 0] = v.x;
    tile[r][lc4 * 4 + 1] = v.y;
    tile[r][lc4 * 4 + 2] = v.z;
    tile[r][lc4 * 4 + 3] = v.w;
  }
  __syncthreads();
  const int rx = (threadIdx.x & 15) * 4;  // output row-quad (src rows)
  const int cy = threadIdx.x >> 4;        // 0..15
#pragma unroll
  for (int i = 0; i < 4; ++i) {
    int c = cy + i * 16;                  // output row = src col
    ushort4 o;
    o.x = f2bf(tile[rx + 0][c]);
    o.y = f2bf(tile[rx + 1][c]);
    o.z = f2bf(tile[rx + 2][c]);
    o.w = f2bf(tile[rx + 3][c]);
    *(ushort4*)&d[(size_t)(c0 + c) * R + r0 + rx] = o;
  }
}

// ---------------------------------------------------------------------------
// Router: logits (fp32 exact), sigmoid, top-2, slot assignment, aux partials
// ---------------------------------------------------------------------------
__global__ __launch_bounds__(256) void router_kernel(
    const float* __restrict__ x, const float* __restrict__ rw,
    const float* __restrict__ rb, int* __restrict__ counts,
    int* __restrict__ expert_of, int* __restrict__ slot_of,
    float* __restrict__ w_of, float* __restrict__ tok_ssq)
{
  const int wave = threadIdx.x >> 6, lane = threadIdx.x & 63;
  const int t = blockIdx.x * 4 + wave;   // one wave per token
  const float4* x4 = (const float4*)(x + (size_t)t * D_);
  const float4* rw4 = (const float4*)rw;
  float acc[E_];
#pragma unroll
  for (int e = 0; e < E_; ++e) acc[e] = 0.f;
#pragma unroll
  for (int d4 = 0; d4 < D_ / 4 / 64; ++d4) {       // 4 iterations
    int idx = d4 * 64 + lane;
    float4 xv = x4[idx];
#pragma unroll
    for (int e = 0; e < E_; ++e) {
      float4 wv = rw4[e * (D_ / 4) + idx];
      acc[e] += xv.x * wv.x + xv.y * wv.y + xv.z * wv.z + xv.w * wv.w;
    }
  }
#pragma unroll
  for (int e = 0; e < E_; ++e) {
    float v = acc[e];
#pragma unroll
    for (int sh = 32; sh > 0; sh >>= 1) v += __shfl_xor(v, sh, 64);
    acc[e] = v;
  }
  if (lane == 0) {
    float logits[E_], sc[E_], ssq = 0.f;
#pragma unroll
    for (int e = 0; e < E_; ++e) {
      logits[e] = acc[e] + rb[e];
      ssq += logits[e] * logits[e];
      sc[e] = 1.f / (1.f + __expf(-logits[e]));
    }
    tok_ssq[t] = ssq;
    int i1 = 0;
#pragma unroll
    for (int e = 1; e < E_; ++e) if (sc[e] > sc[i1]) i1 = e;     // ties -> low idx
    int i2 = (i1 == 0) ? 1 : 0;
#pragma unroll
    for (int e = 0; e < E_; ++e)
      if (e != i1 && e != i2 && sc[e] > sc[i2]) i2 = e;
    float v1 = sc[i1], v2 = sc[i2];
    float inv = 1.f / (v1 + v2 + 1e-6f);
    int s1 = atomicAdd(&counts[i1], 1);
    int s2 = atomicAdd(&counts[i2], 1);
    expert_of[t * 2]     = i1; slot_of[t * 2]     = s1; w_of[t * 2]     = v1 * inv;
    expert_of[t * 2 + 1] = i2; slot_of[t * 2 + 1] = s2; w_of[t * 2 + 1] = v2 * inv;
  }
}

// meta: offsets + compacted tile table (thread 0) + aux-loss reduction (all)
__global__ __launch_bounds__(256) void meta_kernel(
    const int* __restrict__ counts, const float* __restrict__ tok_ssq,
    int* __restrict__ offsets, int* __restrict__ tile_e, int* __restrict__ tile_m0,
    float* __restrict__ out_aux)
{
  if (threadIdx.x == 0) {
    int o = 0, nt = 0;
    for (int e = 0; e < E_; ++e) {
      offsets[e] = o;
      for (int m0 = 0; m0 < counts[e]; m0 += 128) {
        tile_e[nt] = e; tile_m0[nt] = m0; ++nt;
      }
      o += counts[e];
    }
    for (; nt < MAXTILES_; ++nt) tile_e[nt] = -1;
  }
  __shared__ float sm[256];
  float s = 0.f;
  for (int i = threadIdx.x; i < TOK_; i += 256) s += tok_ssq[i];
  sm[threadIdx.x] = s;
  __syncthreads();
  for (int h = 128; h > 0; h >>= 1) {
    if (threadIdx.x < h) sm[threadIdx.x] += sm[threadIdx.x + h];
    __syncthreads();
  }
  if (threadIdx.x == 0) *out_aux = 0.01f * sm[0] / (float)(TOK_ * E_);
}

// ---------------------------------------------------------------------------
// Pack: gather selected token rows (fp32 -> bf16) into compacted A matrix
// ---------------------------------------------------------------------------
__global__ __launch_bounds__(256) void pack_kernel(
    const float* __restrict__ x, const int* __restrict__ expert_of,
    const int* __restrict__ slot_of, const int* __restrict__ offsets,
    unsigned short* __restrict__ px, int* __restrict__ pair_row)
{
  const int pair = blockIdx.x;
  const int t = pair >> 1;
  const int e = expert_of[pair];
  const int row = offsets[e] + slot_of[pair];
  if (threadIdx.x == 0) pair_row[pair] = row;
  const float4* xr = (const float4*)(x + (size_t)t * D_);
  ushort4* pr = (ushort4*)(px + (size_t)row * D_);
  float4 v = xr[threadIdx.x];              // 256 threads x 4 = 1024 elems
  ushort4 o;
  o.x = f2bf(v.x); o.y = f2bf(v.y); o.z = f2bf(v.z); o.w = f2bf(v.w);
  pr[threadIdx.x] = o;
}

// ---------------------------------------------------------------------------
// GEMM staging, BK=64: 128-row x 64-col bf16 tile via global_load_lds w=16.
// LDS layout [row][64] contiguous; XOR swizzle on SOURCE segment:
//   LDS[row][s] = G[row][s ^ (row&7)]  (global_load_lds dest is lane-implicit)
// Frag read of G[row][j*32+lk*8..+8] -> LDS[row][(j*4+lk)^(row&7)] (2-way max).
// Each wave instr covers 8 rows x 128 B contiguous per row.
// ---------------------------------------------------------------------------
__device__ __forceinline__ void stage64(const unsigned short* gbase, int gstride,
                                        unsigned short* sbase, int kk,
                                        int wave, int lane)
{
  const int rw = lane >> 3;                 // 0..7: row within wave-group
  const int seg = (lane & 7) ^ rw;          // swizzled source segment
#pragma unroll
  for (int c = 0; c < 4; ++c) {
    int row = wave * 8 + c * 32 + rw;
    const unsigned short* g = gbase + (size_t)row * gstride + kk + seg * 8;
    unsigned short* s = sbase + (size_t)(wave * 8 + c * 32) * 64;  // wave-uniform
    __builtin_amdgcn_global_load_lds(
        (const __attribute__((address_space(1))) void*)g,
        (__attribute__((address_space(3))) void*)s, 16, 0, 0);
  }
}

__device__ __forceinline__ void stage64_clamped(const unsigned short* gbase, int gstride,
                                                int row0, int rowmax,
                                                unsigned short* sbase, int kk,
                                                int wave, int lane)
{
  const int rw = lane >> 3;
  const int seg = (lane & 7) ^ rw;
#pragma unroll
  for (int c = 0; c < 4; ++c) {
    int row = row0 + wave * 8 + c * 32 + rw;
    row = (row < rowmax) ? row : rowmax - 1;
    const unsigned short* g = gbase + (size_t)row * gstride + kk + seg * 8;
    unsigned short* s = sbase + (size_t)(wave * 8 + c * 32) * 64;
    __builtin_amdgcn_global_load_lds(
        (const __attribute__((address_space(1))) void*)g,
        (__attribute__((address_space(3))) void*)s, 16, 0, 0);
  }
}

__device__ __forceinline__ short8 read_frag64(const unsigned short* smem, int row,
                                              int j, int lk) {
  const int s = (j * 4 + lk) ^ (row & 7);
  return *(const short8*)&smem[row * 64 + s * 8];
}

// ---------------------------------------------------------------------------
// GEMM1 + fused SwiGLU: hid[row][h] = silu(px@w1)[row][h] * (px@w2)[row][h]
// Block: 128 rows x 128 hidden cols (paired tiles h and h+2048). 4 waves 2x2.
// ---------------------------------------------------------------------------
__global__ __launch_bounds__(256, 2) void gemm1_kernel(
    const unsigned short* __restrict__ px, const unsigned short* __restrict__ w12t,
    unsigned short* __restrict__ hid, const int* __restrict__ counts,
    const int* __restrict__ offsets, const int* __restrict__ tile_e,
    const int* __restrict__ tile_m0)
{
  const int ti = blockIdx.y, nt = blockIdx.x;
  const int e = tile_e[ti];
  if (e < 0) return;
  const int m0 = tile_m0[ti];
  const int cnt = counts[e];
  const int off = offsets[e];
  const int tid = threadIdx.x;
  const int wave = tid >> 6, lane = tid & 63;
  const int wm = wave >> 1, wn = wave & 1;
  const int lr = lane & 15, lk = lane >> 4;

  __shared__ __align__(16) unsigned short As[128 * 64];
  __shared__ __align__(16) unsigned short B1s[128 * 64];
  __shared__ __align__(16) unsigned short B2s[128 * 64];

  f32x4 zero = {0.f, 0.f, 0.f, 0.f};
  f32x4 acc1[4][4], acc2[4][4];
#pragma unroll
  for (int mi = 0; mi < 4; ++mi)
#pragma unroll
    for (int ni = 0; ni < 4; ++ni) { acc1[mi][ni] = zero; acc2[mi][ni] = zero; }

  const unsigned short* B1base = w12t + ((size_t)e * N1_ + nt * 128) * D_;
  const unsigned short* B2base = w12t + ((size_t)e * N1_ + H_ + nt * 128) * D_;

  for (int kk = 0; kk < D_; kk += 64) {
    stage64_clamped(px, D_, off + m0, PAIRS_, As, kk, wave, lane);
    stage64(B1base, D_, B1s, kk, wave, lane);
    stage64(B2base, D_, B2s, kk, wave, lane);
    __syncthreads();
#pragma unroll
    for (int j = 0; j < 2; ++j) {
      short8 a[4], b1[4], b2[4];
#pragma unroll
      for (int i = 0; i < 4; ++i) {
        a[i]  = read_frag64(As,  wm * 64 + i * 16 + lr, j, lk);
        b1[i] = read_frag64(B1s, wn * 64 + i * 16 + lr, j, lk);
        b2[i] = read_frag64(B2s, wn * 64 + i * 16 + lr, j, lk);
      }
#pragma unroll
      for (int mi = 0; mi < 4; ++mi)
#pragma unroll
        for (int ni = 0; ni < 4; ++ni) {
          acc1[mi][ni] = __builtin_amdgcn_mfma_f32_16x16x32_bf16(a[mi], b1[ni], acc1[mi][ni], 0, 0, 0);
          acc2[mi][ni] = __builtin_amdgcn_mfma_f32_16x16x32_bf16(a[mi], b2[ni], acc2[mi][ni], 0, 0, 0);
        }
    }
    __syncthreads();
  }

  // epilogue: SwiGLU + bf16 store (C/D layout: col=lane&15, row=(lane>>4)*4+r)
#pragma unroll
  for (int mi = 0; mi < 4; ++mi)
#pragma unroll
    for (int r = 0; r < 4; ++r) {
      int row_local = m0 + wm * 64 + mi * 16 + lk * 4 + r;
      if (row_local < cnt) {
#pragma unroll
        for (int ni = 0; ni < 4; ++ni) {
          int col = nt * 128 + wn * 64 + ni * 16 + lr;
          float v1 = acc1[mi][ni][r];
          float v2 = acc2[mi][ni][r];
          float hval = (v1 / (1.f + __expf(-v1))) * v2;
          hid[(size_t)(off + row_local) * H_ + col] = f2bf(hval);
        }
      }
    }
}

// ---------------------------------------------------------------------------
// GEMM2: ybuf[ks][row][d] = (hid @ w3t^T) over K-half ks.  bf16 stores.
// ---------------------------------------------------------------------------
__global__ __launch_bounds__(256, 4) void gemm2_kernel(
    const unsigned short* __restrict__ hid, const unsigned short* __restrict__ w3t,
    const int* __restrict__ counts, const int* __restrict__ offsets,
    const int* __restrict__ tile_e, const int* __restrict__ tile_m0,
    unsigned short* __restrict__ ybuf)
{
  const int ti = blockIdx.y, nt = blockIdx.x, ks = blockIdx.z;
  const int e = tile_e[ti];
  if (e < 0) return;
  const int m0 = tile_m0[ti];
  const int cnt = counts[e];
  const int off = offsets[e];
  const int tid = threadIdx.x;
  const int wave = tid >> 6, lane = tid & 63;
  const int wm = wave >> 1, wn = wave & 1;
  const int lr = lane & 15, lk = lane >> 4;

  __shared__ __align__(16) unsigned short As[128 * 64];
  __shared__ __align__(16) unsigned short Bs[128 * 64];

  f32x4 zero = {0.f, 0.f, 0.f, 0.f};
  f32x4 acc[4][4];
#pragma unroll
  for (int mi = 0; mi < 4; ++mi)
#pragma unroll
    for (int ni = 0; ni < 4; ++ni) acc[mi][ni] = zero;

  const unsigned short* Bbase = w3t + ((size_t)e * D_ + nt * 128) * H_;
  unsigned short* yb = ybuf + (size_t)ks * PAIRS_ * D_;

  const int k0 = ks * (H_ / 2), k1 = k0 + (H_ / 2);
  for (int kk = k0; kk < k1; kk += 64) {
    stage64_clamped(hid, H_, off + m0, PAIRS_, As, kk, wave, lane);
    stage64(Bbase, H_, Bs, kk, wave, lane);
    __syncthreads();
#pragma unroll
    for (int j = 0; j < 2; ++j) {
      short8 a[4], b[4];
#pragma unroll
      for (int i = 0; i < 4; ++i) {
        a[i] = read_frag64(As, wm * 64 + i * 16 + lr, j, lk);
        b[i] = read_frag64(Bs, wn * 64 + i * 16 + lr, j, lk);
      }
#pragma unroll
      for (int mi = 0; mi < 4; ++mi)
#pragma unroll
        for (int ni = 0; ni < 4; ++ni)
          acc[mi][ni] = __builtin_amdgcn_mfma_f32_16x16x32_bf16(a[mi], b[ni], acc[mi][ni], 0, 0, 0);
    }
    __syncthreads();
  }

#pragma unroll
  for (int mi = 0; mi < 4; ++mi)
#pragma unroll
    for (int r = 0; r < 4; ++r) {
      int row_local = m0 + wm * 64 + mi * 16 + lk * 4 + r;
      if (row_local < cnt) {
        int g = off + row_local;
#pragma unroll
        for (int ni = 0; ni < 4; ++ni) {
          int col = nt * 128 + wn * 64 + ni * 16 + lr;
          yb[(size_t)g * D_ + col] = f2bf(acc[mi][ni][r]);
        }
      }
    }
}

// ---------------------------------------------------------------------------
// Combine: out[t][d] = w0*(y0[r0][d]+y1[r0][d]) + w1*(y0[r1][d]+y1[r1][d])
// ---------------------------------------------------------------------------
__global__ __launch_bounds__(256) void combine_kernel(
    const unsigned short* __restrict__ ybuf, const int* __restrict__ pair_row,
    const float* __restrict__ w_of, float* __restrict__ out)
{
  const int t = blockIdx.x;
  const int r0 = pair_row[t * 2], r1 = pair_row[t * 2 + 1];
  const float w0 = w_of[t * 2], w1 = w_of[t * 2 + 1];
  const unsigned short* y1p = ybuf + (size_t)PAIRS_ * D_;
  const int i = threadIdx.x;               // 256 threads x 4 elems
  ushort4 a0 = *(const ushort4*)&ybuf[(size_t)r0 * D_ + i * 4];
  ushort4 b0 = *(const ushort4*)&y1p [(size_t)r0 * D_ + i * 4];
  ushort4 a1 = *(const ushort4*)&ybuf[(size_t)r1 * D_ + i * 4];
  ushort4 b1 = *(const ushort4*)&y1p [(size_t)r1 * D_ + i * 4];
  float4 o;
  o.x = w0 * (bf2f(a0.x) + bf2f(b0.x)) + w1 * (bf2f(a1.x) + bf2f(b1.x));
  o.y = w0 * (bf2f(a0.y) + bf2f(b0.y)) + w1 * (bf2f(a1.y) + bf2f(b1.y));
  o.z = w0 * (bf2f(a0.z) + bf2f(b0.z)) + w1 * (bf2f(a1.z) + bf2f(b1.z));
  o.w = w0 * (bf2f(a0.w) + bf2f(b0.w)) + w1 * (bf2f(a1.w) + bf2f(b1.w));
  ((float4*)out)[(size_t)t * (D_ / 4) + i] = o;
}

// ---------------------------------------------------------------------------
extern "C" void kernel_launch(void* const* d_in, const int* in_sizes, int n_in,
                              void* d_out, int out_size, void* d_ws, size_t ws_size,
                              hipStream_t stream)
{
  const float* x   = (const float*)d_in[0];
  const float* rw  = (const float*)d_in[1];
  const float* rb  = (const float*)d_in[2];
  const float* w12 = (const float*)d_in[3];
  const float* w3  = (const float*)d_in[4];
  float* out = (float*)d_out;

  // workspace layout (~136.1 MB total)
  char* wsb = (char*)d_ws;
  int*   counts    = (int*)(wsb + 0);                 // 8 ints
  int*   offsets   = (int*)(wsb + 64);                // 8 ints
  int*   tile_e    = (int*)(wsb + 128);               // 40 ints
  int*   tile_m0   = (int*)(wsb + 384);               // 40 ints
  int*   expert_of = (int*)(wsb + 1024);              // 4096 ints
  int*   slot_of   = (int*)(wsb + 1024 + 16384);
  float* w_of      = (float*)(wsb + 1024 + 2 * 16384);
  int*   pair_row  = (int*)(wsb + 1024 + 3 * 16384);
  float* tok_ssq   = (float*)(wsb + 1024 + 4 * 16384);        // 2048 floats
  unsigned short* px   = (unsigned short*)(wsb + (128 << 10));                          // 8 MB
  unsigned short* hid  = (unsigned short*)(wsb + (128 << 10) + ((size_t)8  << 20));     // 16 MB
  unsigned short* w12t = (unsigned short*)(wsb + (128 << 10) + ((size_t)24 << 20));     // 64 MB
  unsigned short* w3t  = (unsigned short*)(wsb + (128 << 10) + ((size_t)88 << 20));     // 32 MB
  unsigned short* ybuf = (unsigned short*)(wsb + (128 << 10) + ((size_t)120 << 20));    // 16 MB

  hipMemsetAsync(counts, 0, E_ * sizeof(int), stream);

  transpose_f32_to_bf16<<<dim3(N1_ / 64, D_ / 64, E_), 256, 0, stream>>>(w12, w12t, D_, N1_);
  transpose_f32_to_bf16<<<dim3(D_ / 64, H_ / 64, E_), 256, 0, stream>>>(w3, w3t, H_, D_);
  router_kernel<<<TOK_ / 4, 256, 0, stream>>>(x, rw, rb, counts, expert_of, slot_of, w_of, tok_ssq);
  meta_kernel<<<1, 256, 0, stream>>>(counts, tok_ssq, offsets, tile_e, tile_m0, out + (size_t)TOK_ * D_);
  pack_kernel<<<PAIRS_, 256, 0, stream>>>(x, expert_of, slot_of, offsets, px, pair_row);
  gemm1_kernel<<<dim3(16, MAXTILES_), 256, 0, stream>>>(px, w12t, hid, counts, offsets, tile_e, tile_m0);
  gemm2_kernel<<<dim3(8, MAXTILES_, 2), 256, 0, stream>>>(hid, w3t, counts, offsets, tile_e, tile_m0, ybuf);
  combine_kernel<<<TOK_, 256, 0, stream>>>(ybuf, pair_row, w_of, out);
}